// Round 22
// baseline (131.809 us; speedup 1.0000x reference)
//
#include <hip/hip_runtime.h>
#include <hip/hip_bf16.h>
#include <stdint.h>

// z_e (32,64,64,64) f32, codebook (512,64) f32.
// d_out (f32): [0..8388607] z_q (B,C,H,W); [8388608] loss; [8388609..] indices as float.
#define NPIX 131072
#define CDIM 64
#define KCODES 512
#define ZQ_SIZE 8388608
#define LOSS_OFF 8388608
#define IDXOUT_OFF 8388609
#define CH_STRIDE 4096
#define B_STRIDE 262144
#define MARGIN_UNITS 512       // 256u ref-grid noise (R5-validated) + 8.5*sigma(30u) f16 err
#define SCALE 4194304.0f       // 2^22
#define BIAS 0.5f

typedef __attribute__((ext_vector_type(8))) _Float16 half8v;  // 8 f16 (4 VGPRs)
typedef __attribute__((ext_vector_type(16))) float f32x16;
typedef __attribute__((ext_vector_type(4))) float f32x4;
typedef __attribute__((ext_vector_type(4))) int i32x4;

// ws layout:
//   0       double loss
//   64      float  c2_ref[512]   (numpy pairwise-8, for exact resolve)
//   2112    float  c2fix[512]    ((||c||^2+0.5)*2^22)
//   4160    ushort cb_f16 chunks [g][code][8 f16], c*2048  (65536 B) — L2-resident
//   69696   float  cbT[64][512]  (131072 B, exact f32 for resolve)
#define WS_C2REF 64
#define WS_C2FIX 2112
#define WS_CBH   4160
#define WS_CBT   69696

__device__ __forceinline__ unsigned short f2h_bits(float v) {
    _Float16 h = (_Float16)v;            // v_cvt_f16_f32, RNE
    unsigned short u;
    __builtin_memcpy(&u, &h, 2);
    return u;
}

__global__ void k0_prep(const float* __restrict__ cb, char* __restrict__ ws) {
#pragma clang fp contract(off)
    int k = blockIdx.x * 64 + threadIdx.x;
    if (k >= KCODES) return;
    const float* cr = cb + (size_t)k * CDIM;
    float r[8];
    #pragma unroll
    for (int j = 0; j < 8; ++j) r[j] = cr[j] * cr[j];
    #pragma unroll
    for (int t = 1; t < 8; ++t)
        #pragma unroll
        for (int j = 0; j < 8; ++j) r[j] += cr[8 * t + j] * cr[8 * t + j];
    ((float*)(ws + WS_C2REF))[k] = ((r[0] + r[1]) + (r[2] + r[3])) + ((r[4] + r[5]) + (r[6] + r[7]));
    float acc = 0.f;
    #pragma unroll
    for (int i = 0; i < CDIM; ++i) acc = fmaf(cr[i], cr[i], acc);
    ((float*)(ws + WS_C2FIX))[k] = (acc + BIAS) * SCALE;
    unsigned short* hi = (unsigned short*)(ws + WS_CBH);
    #pragma unroll
    for (int g = 0; g < 8; ++g)
        #pragma unroll
        for (int j = 0; j < 8; ++j)
            hi[((size_t)(g * KCODES + k)) * 8 + j] = f2h_bits(cr[g * 8 + j] * 2048.0f);
    float* cbT = (float*)(ws + WS_CBT);
    #pragma unroll
    for (int i = 0; i < CDIM; ++i) cbT[i * KCODES + k] = cr[i];
}

// 512 threads = 8 waves, 256 px/block, grid 512 blocks.
// NO LDS codebook: cb_f16 + c2fix read from L2 (64KB shared, always hot).
// LDS ~2.1KB static -> residency VGPR-capped: launch_bounds(512,6) -> 80 VGPR,
// 6 waves/EU = 24 waves/CU = 3 blocks/CU (3x R21 TLP), no staging barrier.
__global__ __launch_bounds__(512, 6)
void k1_mfma(const float* __restrict__ z_e,
             const float* __restrict__ cb,
             char* __restrict__ ws,
             float* __restrict__ out) {
#pragma clang fp contract(off)
    __shared__ int    queue[256];
    __shared__ int    qcnt;
    __shared__ double wls[8];
    __shared__ int    idxs[256];

    const int tid  = threadIdx.x;
    const int lane = tid & 63;
    const int wav  = tid >> 6;          // 0..7
    const int h    = lane >> 5;
    const int c    = lane & 31;

    const int pxblk = blockIdx.x * 256;
    const int b     = pxblk >> 12;
    const int hwb   = pxblk & 4095;
    const float* zb = z_e + (size_t)b * B_STRIDE;

    if (tid == 0) qcnt = 0;

    const int lpx = wav * 32 + c;        // block-local pixel (0..255)
    const int hw  = hwb + lpx;

    // ---- z fragments: f16(-4096*z), single chain
    half8v zh[4];
    #pragma unroll
    for (int s = 0; s < 4; ++s) {
        float zf[8];
        #pragma unroll
        for (int j = 0; j < 8; ++j)
            zf[j] = zb[(size_t)(s * 16 + h * 8 + j) * CH_STRIDE + hw];
        half8v vh;
        #pragma unroll
        for (int j = 0; j < 8; ++j)
            vh[j] = (_Float16)(zf[j] * -4096.0f);
        zh[s] = vh;
    }

    // ---- MFMA scores + fixed-point min-track (cb_f16 + c2fix from L2)
    const half8v* hi_chunks = (const half8v*)(ws + WS_CBH);
    const float*  c2fg      = (const float*)(ws + WS_C2FIX);
    uint32_t m1 = 0xFFFFFFFFu, m2 = 0xFFFFFFFFu;

    for (int t = 0; t < 16; ++t) {
        int rbase = t * 32 + 4 * h;
        f32x16 acc;
        #pragma unroll
        for (int g = 0; g < 4; ++g) {
            f32x4 q = *(const f32x4*)(c2fg + rbase + 8 * g);   // broadcast, L2-hot
            #pragma unroll
            for (int i = 0; i < 4; ++i) acc[4 * g + i] = q[i];
        }
        #pragma unroll
        for (int s = 0; s < 4; ++s) {
            int chunk = (2 * s + h) * KCODES + t * 32 + c;
            half8v a = hi_chunks[chunk];                        // 512B coalesced, L2-hot
            acc = __builtin_amdgcn_mfma_f32_32x32x16_f16(a, zh[s], acc, 0, 0, 0);
        }
        #pragma unroll
        for (int i = 0; i < 16; ++i) {
            uint32_t code = (uint32_t)(t * 32 + 4 * h + (i & 3) + 8 * (i >> 2));
            uint32_t u = (((uint32_t)acc[i]) << 9) | code;
            uint32_t mx = m1 > u ? m1 : u;
            m2 = m2 < mx ? m2 : mx;
            m1 = m1 < u ? m1 : u;
        }
    }

    {   // merge lanes l and l^32 (same pixel)
        uint32_t o1 = (uint32_t)__shfl_xor((int)m1, 32);
        uint32_t o2 = (uint32_t)__shfl_xor((int)m2, 32);
        uint32_t mx  = m1 > o1 ? m1 : o1;
        uint32_t mn2 = m2 < o2 ? m2 : o2;
        m2 = mn2 < mx ? mn2 : mx;
        m1 = m1 < o1 ? m1 : o1;
    }

    __syncthreads();   // orders qcnt=0 before the atomicAdd below

    // provisional idx + flag queue (owner lane h==0)
    if (h == 0) {
        idxs[lpx] = (int)(m1 & 0x1FFu);
        if ((int)((m2 >> 9) - (m1 >> 9)) < MARGIN_UNITS) {
            int pos = atomicAdd(&qcnt, 1);
            queue[pos] = lpx;
        }
    }
    __syncthreads();

    // ---- batched exact resolve (R12/R16-verified reference math), 8-wave distributed
    {
        const float* c2r = (const float*)(ws + WS_C2REF);
        const float* cbT = (const float*)(ws + WS_CBT);
        const int nf = qcnt;
        #pragma unroll 1
        for (int q = wav; q < nf; q += 8) {
            int pl = queue[q];
            int hwq = hwb + pl;
            float a[8] = {0.f,0.f,0.f,0.f,0.f,0.f,0.f,0.f};
            float r[8] = {0.f,0.f,0.f,0.f,0.f,0.f,0.f,0.f};
            #pragma unroll 1
            for (int ib = 0; ib < 8; ++ib) {
                float zr[8];
                #pragma unroll
                for (int i = 0; i < 8; ++i)
                    zr[i] = zb[(size_t)(ib * 8 + i) * CH_STRIDE + hwq];  // uniform, L3-hot
                #pragma unroll
                for (int i = 0; i < 8; ++i) {
                    float zi = zr[i];
                    r[i] += zi * zi;                       // ref pairwise-8 order (i ascending)
                    const float* ct = cbT + (size_t)(ib * 8 + i) * KCODES + lane;
                    #pragma unroll
                    for (int k = 0; k < 8; ++k)
                        a[k] = fmaf(zi, ct[k * 64], a[k]); // ascending i per code
                }
            }
            float A = ((r[0] + r[1]) + (r[2] + r[3])) + ((r[4] + r[5]) + (r[6] + r[7]));
            float best = 3.4e38f; int bidx = 0x7FFFFFFF;
            #pragma unroll
            for (int k = 0; k < 8; ++k) {
                float d = (A - 2.0f * a[k]) + c2r[k * 64 + lane];
                if (d < best) { best = d; bidx = k * 64 + lane; }
            }
            for (int off = 32; off; off >>= 1) {
                float ob = __shfl_down(best, off);
                int   oi = __shfl_down(bidx, off);
                if (ob < best || (ob == best && oi < bidx)) { best = ob; bidx = oi; }
            }
            if (lane == 0) idxs[pl] = bidx;
        }
    }
    __syncthreads();

    // ---- epilogue A: idx out + loss (z reconstructed from zh f16: R21-validated)
    {
        int idxv = idxs[lpx];
        if (h == 0) out[IDXOUT_OFF + pxblk + lpx] = (float)idxv;
        const float* crow = cb + (size_t)idxv * CDIM;
        float lsum = 0.f;
        #pragma unroll
        for (int s = 0; s < 4; ++s) {
            int ch0 = s * 16 + h * 8;
            f32x4 g0 = *(const f32x4*)(crow + ch0);
            f32x4 g1 = *(const f32x4*)(crow + ch0 + 4);
            #pragma unroll
            for (int j = 0; j < 8; ++j) {
                float zq = (j < 4) ? g0[j] : g1[j - 4];
                float zv = (float)zh[s][j] * -2.44140625e-4f;
                float d = zq - zv;
                lsum = fmaf(d, d, lsum);
            }
        }
        double dl = (double)lsum;
        for (int off = 32; off; off >>= 1) dl += __shfl_down(dl, off);
        if (lane == 0) wls[wav] = dl;
    }

    // ---- epilogue B: streaming z_q write (1KB contiguous per store across a wave)
    {
        int px0 = lane * 4;                       // 4 consecutive pixels (0..255)
        i32x4 i4 = *(const i32x4*)&idxs[px0];
        float* obase = out + (size_t)b * B_STRIDE + hwb;
        #pragma unroll
        for (int p = 0; p < 8; ++p) {
            int ch = p * 8 + wav;                 // each wave: 8 channels
            f32x4 v;
            v[0] = cb[(size_t)i4[0] * CDIM + ch];
            v[1] = cb[(size_t)i4[1] * CDIM + ch];
            v[2] = cb[(size_t)i4[2] * CDIM + ch];
            v[3] = cb[(size_t)i4[3] * CDIM + ch];
            *(f32x4*)(obase + (size_t)ch * CH_STRIDE + px0) = v;
        }
    }

    __syncthreads();
    if (tid == 0) {
        double s = 0.0;
        #pragma unroll
        for (int i = 0; i < 8; ++i) s += wls[i];
        atomicAdd((double*)ws, s);
    }
}

__global__ void k4_loss(float* __restrict__ out, const double* __restrict__ loss_acc) {
    out[LOSS_OFF] = (float)(1.25 * (*loss_acc) / (double)ZQ_SIZE);
}

extern "C" void kernel_launch(void* const* d_in, const int* in_sizes, int n_in,
                              void* d_out, int out_size, void* d_ws, size_t ws_size,
                              hipStream_t stream) {
    const float* z_e = (const float*)d_in[0];
    const float* cb  = (const float*)d_in[1];
    float* out = (float*)d_out;
    char* ws = (char*)d_ws;

    hipMemsetAsync(ws, 0, 64, stream);
    k0_prep<<<8, 64, 0, stream>>>(cb, ws);
    k1_mfma<<<NPIX / 256, 512, 0, stream>>>(z_e, cb, ws, out);
    k4_loss<<<1, 1, 0, stream>>>(out, (const double*)ws);
}

// Round 23
// 81.357 us; speedup vs baseline: 1.6201x; 1.6201x over previous
//
#include <hip/hip_runtime.h>
#include <hip/hip_bf16.h>
#include <stdint.h>

// z_e (32,64,64,64) f32, codebook (512,64) f32.
// d_out (f32): [0..8388607] z_q (B,C,H,W); [8388608] loss; [8388609..] indices as float.
#define NPIX 131072
#define CDIM 64
#define KCODES 512
#define ZQ_SIZE 8388608
#define LOSS_OFF 8388608
#define IDXOUT_OFF 8388609
#define CH_STRIDE 4096
#define B_STRIDE 262144
#define MARGIN_UNITS 512       // 256u ref-grid noise + 8.5*sigma f16 err (R21-verified)
#define SCALE 4194304.0f       // 2^22
#define BIAS 0.5f

typedef __attribute__((ext_vector_type(8))) _Float16 half8v;  // 8 f16 (4 VGPRs)
typedef __attribute__((ext_vector_type(16))) float f32x16;
typedef __attribute__((ext_vector_type(4))) float f32x4;
typedef __attribute__((ext_vector_type(4))) int i32x4;

// ws layout:
//   0       double loss
//   64      float  c2_ref[512]   (numpy pairwise-8, for exact resolve)
//   2112    float  c2fix[512]    ((||c||^2+0.5)*2^22)
//   4160    ushort cb_f16 chunks [g][code][8 f16], c*2048  (65536 B)
//   69696   float  cbT[64][512]  (131072 B, exact f32 for resolve)
#define WS_C2REF 64
#define WS_C2FIX 2112
#define WS_CBH   4160
#define WS_CBT   69696

// LDS layout (71.9 KB; f16 live set ~48 fits the 64-VGPR allocation -> no spill):
#define L_CBH   0          // 65536
#define L_C2F   65536      // 2048
#define L_QUEUE 67584      // int[512]
#define L_QCNT  69632      // int (+pad)
#define L_WLS   69696      // double[16]
#define L_IDXS  69824      // int[512]
#define LDS_SZ  71872

__device__ __forceinline__ unsigned short f2h_bits(float v) {
    _Float16 h = (_Float16)v;            // v_cvt_f16_f32, RNE
    unsigned short u;
    __builtin_memcpy(&u, &h, 2);
    return u;
}

__global__ void k0_prep(const float* __restrict__ cb, char* __restrict__ ws) {
#pragma clang fp contract(off)
    int k = blockIdx.x * 64 + threadIdx.x;
    if (k >= KCODES) return;
    const float* cr = cb + (size_t)k * CDIM;
    float r[8];
    #pragma unroll
    for (int j = 0; j < 8; ++j) r[j] = cr[j] * cr[j];
    #pragma unroll
    for (int t = 1; t < 8; ++t)
        #pragma unroll
        for (int j = 0; j < 8; ++j) r[j] += cr[8 * t + j] * cr[8 * t + j];
    ((float*)(ws + WS_C2REF))[k] = ((r[0] + r[1]) + (r[2] + r[3])) + ((r[4] + r[5]) + (r[6] + r[7]));
    float acc = 0.f;
    #pragma unroll
    for (int i = 0; i < CDIM; ++i) acc = fmaf(cr[i], cr[i], acc);
    ((float*)(ws + WS_C2FIX))[k] = (acc + BIAS) * SCALE;
    unsigned short* hi = (unsigned short*)(ws + WS_CBH);
    #pragma unroll
    for (int g = 0; g < 8; ++g)
        #pragma unroll
        for (int j = 0; j < 8; ++j)
            hi[((size_t)(g * KCODES + k)) * 8 + j] = f2h_bits(cr[g * 8 + j] * 2048.0f);
    float* cbT = (float*)(ws + WS_CBT);
    #pragma unroll
    for (int i = 0; i < CDIM; ++i) cbT[i * KCODES + k] = cr[i];
}

// 1024 threads = 16 waves, 512 contiguous pixels/block, 256 blocks.
// R21 f16 single-chain math in the R16 structure: live ~48 VGPR < 64 cap.
__global__ __launch_bounds__(1024)
void k1_mfma(const float* __restrict__ z_e,
             const float* __restrict__ cb,
             char* __restrict__ ws,
             float* __restrict__ out) {
#pragma clang fp contract(off)
    extern __shared__ char smem[];
    int*    queue = (int*)(smem + L_QUEUE);
    int*    qcnt  = (int*)(smem + L_QCNT);
    double* wls   = (double*)(smem + L_WLS);
    int*    idxs  = (int*)(smem + L_IDXS);

    const int tid  = threadIdx.x;
    const int lane = tid & 63;
    const int wav  = tid >> 6;          // 0..15
    const int h    = lane >> 5;
    const int c    = lane & 31;

    const int pxblk = blockIdx.x * 512;
    const int b     = pxblk >> 12;
    const int hwb   = pxblk & 4095;
    const float* zb = z_e + (size_t)b * B_STRIDE;

    // ---- stage cb_f16 (64KB) + c2fix (2KB) to LDS
    if (tid == 0) *qcnt = 0;
    {
        const uint4* src = (const uint4*)(ws + WS_CBH);
        uint4* dst = (uint4*)smem;
        #pragma unroll
        for (int i = 0; i < 4; ++i)
            dst[i * 1024 + tid] = src[i * 1024 + tid];
        if (tid < 128)
            ((uint4*)(smem + L_C2F))[tid] = ((const uint4*)(ws + WS_C2FIX))[tid];
    }
    __syncthreads();

    const int lpx = wav * 32 + c;        // block-local pixel (0..511)
    const int hw  = hwb + lpx;

    // ---- z fragments: f16(-4096*z), single chain (R21-verified)
    half8v zh[4];
    #pragma unroll
    for (int s = 0; s < 4; ++s) {
        float zf[8];
        #pragma unroll
        for (int j = 0; j < 8; ++j)
            zf[j] = zb[(size_t)(s * 16 + h * 8 + j) * CH_STRIDE + hw];
        half8v vh;
        #pragma unroll
        for (int j = 0; j < 8; ++j)
            vh[j] = (_Float16)(zf[j] * -4096.0f);
        zh[s] = vh;
    }

    // ---- MFMA scores + fixed-point min-track (cb_f16 from LDS)
    const float* c2f = (const float*)(smem + L_C2F);
    uint32_t m1 = 0xFFFFFFFFu, m2 = 0xFFFFFFFFu;

    for (int t = 0; t < 16; ++t) {
        int rbase = t * 32 + 4 * h;
        f32x16 acc;
        #pragma unroll
        for (int g = 0; g < 4; ++g) {
            f32x4 q = *(const f32x4*)(c2f + rbase + 8 * g);
            #pragma unroll
            for (int i = 0; i < 4; ++i) acc[4 * g + i] = q[i];
        }
        #pragma unroll
        for (int s = 0; s < 4; ++s) {
            int chunk = (2 * s + h) * KCODES + t * 32 + c;
            half8v a = *(const half8v*)(smem + L_CBH + (size_t)chunk * 16);
            acc = __builtin_amdgcn_mfma_f32_32x32x16_f16(a, zh[s], acc, 0, 0, 0);
        }
        #pragma unroll
        for (int i = 0; i < 16; ++i) {
            uint32_t code = (uint32_t)(t * 32 + 4 * h + (i & 3) + 8 * (i >> 2));
            uint32_t u = (((uint32_t)acc[i]) << 9) | code;
            uint32_t mx = m1 > u ? m1 : u;
            m2 = m2 < mx ? m2 : mx;
            m1 = m1 < u ? m1 : u;
        }
    }

    {   // merge lanes l and l^32 (same pixel)
        uint32_t o1 = (uint32_t)__shfl_xor((int)m1, 32);
        uint32_t o2 = (uint32_t)__shfl_xor((int)m2, 32);
        uint32_t mx  = m1 > o1 ? m1 : o1;
        uint32_t mn2 = m2 < o2 ? m2 : o2;
        m2 = mn2 < mx ? mn2 : mx;
        m1 = m1 < o1 ? m1 : o1;
    }

    // provisional idx + flag queue (owner lane h==0)
    if (h == 0) {
        idxs[lpx] = (int)(m1 & 0x1FFu);
        if ((int)((m2 >> 9) - (m1 >> 9)) < MARGIN_UNITS) {
            int pos = atomicAdd(qcnt, 1);
            queue[pos] = lpx;
        }
    }
    __syncthreads();

    // ---- batched exact resolve (R12/R16/R21-verified reference math), 16-wave
    {
        const float* c2r = (const float*)(ws + WS_C2REF);
        const float* cbT = (const float*)(ws + WS_CBT);
        const int nf = *qcnt;
        #pragma unroll 1
        for (int q = wav; q < nf; q += 16) {
            int pl = queue[q];
            int hwq = hwb + pl;
            float a[8] = {0.f,0.f,0.f,0.f,0.f,0.f,0.f,0.f};
            float r[8] = {0.f,0.f,0.f,0.f,0.f,0.f,0.f,0.f};
            #pragma unroll 1
            for (int ib = 0; ib < 8; ++ib) {
                float zr[8];
                #pragma unroll
                for (int i = 0; i < 8; ++i)
                    zr[i] = zb[(size_t)(ib * 8 + i) * CH_STRIDE + hwq];  // uniform, L3-hot
                #pragma unroll
                for (int i = 0; i < 8; ++i) {
                    float zi = zr[i];
                    r[i] += zi * zi;                       // ref pairwise-8 order (i ascending)
                    const float* ct = cbT + (size_t)(ib * 8 + i) * KCODES + lane;
                    #pragma unroll
                    for (int k = 0; k < 8; ++k)
                        a[k] = fmaf(zi, ct[k * 64], a[k]); // ascending i per code
                }
            }
            float A = ((r[0] + r[1]) + (r[2] + r[3])) + ((r[4] + r[5]) + (r[6] + r[7]));
            float best = 3.4e38f; int bidx = 0x7FFFFFFF;
            #pragma unroll
            for (int k = 0; k < 8; ++k) {
                float d = (A - 2.0f * a[k]) + c2r[k * 64 + lane];
                if (d < best) { best = d; bidx = k * 64 + lane; }
            }
            for (int off = 32; off; off >>= 1) {
                float ob = __shfl_down(best, off);
                int   oi = __shfl_down(bidx, off);
                if (ob < best || (ob == best && oi < bidx)) { best = ob; bidx = oi; }
            }
            if (lane == 0) idxs[pl] = bidx;
        }
    }
    __syncthreads();

    // ---- epilogue A: idx out + loss (z reconstructed from zh f16: R21-validated)
    {
        int idxv = idxs[lpx];
        if (h == 0) out[IDXOUT_OFF + pxblk + lpx] = (float)idxv;
        const float* crow = cb + (size_t)idxv * CDIM;
        float lsum = 0.f;
        #pragma unroll
        for (int s = 0; s < 4; ++s) {
            int ch0 = s * 16 + h * 8;
            f32x4 g0 = *(const f32x4*)(crow + ch0);
            f32x4 g1 = *(const f32x4*)(crow + ch0 + 4);
            #pragma unroll
            for (int j = 0; j < 8; ++j) {
                float zq = (j < 4) ? g0[j] : g1[j - 4];
                float zv = (float)zh[s][j] * -2.44140625e-4f;
                float d = zq - zv;
                lsum = fmaf(d, d, lsum);
            }
        }
        double dl = (double)lsum;
        for (int off = 32; off; off >>= 1) dl += __shfl_down(dl, off);
        if (lane == 0) wls[wav] = dl;
    }

    // ---- epilogue B: streaming z_q write (1KB contiguous per store across a wave)
    {
        int px0 = (wav & 1) * 256 + lane * 4;     // 4 consecutive pixels
        int chb = wav >> 1;                       // channel sub-lane 0..7
        i32x4 i4 = *(const i32x4*)&idxs[px0];
        float* obase = out + (size_t)b * B_STRIDE + hwb;
        #pragma unroll
        for (int p = 0; p < 8; ++p) {
            int ch = p * 8 + chb;
            f32x4 v;
            v[0] = cb[(size_t)i4[0] * CDIM + ch];
            v[1] = cb[(size_t)i4[1] * CDIM + ch];
            v[2] = cb[(size_t)i4[2] * CDIM + ch];
            v[3] = cb[(size_t)i4[3] * CDIM + ch];
            *(f32x4*)(obase + (size_t)ch * CH_STRIDE + px0) = v;
        }
    }

    __syncthreads();
    if (tid == 0) {
        double s = 0.0;
        #pragma unroll
        for (int i = 0; i < 16; ++i) s += wls[i];
        atomicAdd((double*)ws, s);
    }
}

__global__ void k4_loss(float* __restrict__ out, const double* __restrict__ loss_acc) {
    out[LOSS_OFF] = (float)(1.25 * (*loss_acc) / (double)ZQ_SIZE);
}

extern "C" void kernel_launch(void* const* d_in, const int* in_sizes, int n_in,
                              void* d_out, int out_size, void* d_ws, size_t ws_size,
                              hipStream_t stream) {
    const float* z_e = (const float*)d_in[0];
    const float* cb  = (const float*)d_in[1];
    float* out = (float*)d_out;
    char* ws = (char*)d_ws;

    hipMemsetAsync(ws, 0, 64, stream);
    k0_prep<<<8, 64, 0, stream>>>(cb, ws);
    k1_mfma<<<NPIX / 512, 1024, LDS_SZ, stream>>>(z_e, cb, ws, out);
    k4_loss<<<1, 1, 0, stream>>>(out, (const double*)ws);
}

// Round 24
// 76.958 us; speedup vs baseline: 1.7127x; 1.0572x over previous
//
#include <hip/hip_runtime.h>
#include <hip/hip_bf16.h>
#include <stdint.h>

// z_e (32,64,64,64) f32, codebook (512,64) f32.
// d_out (f32): [0..8388607] z_q (B,C,H,W); [8388608] loss; [8388609..] indices as float.
#define NPIX 131072
#define CDIM 64
#define KCODES 512
#define ZQ_SIZE 8388608
#define LOSS_OFF 8388608
#define IDXOUT_OFF 8388609
#define CH_STRIDE 4096
#define B_STRIDE 262144
#define MARGIN_UNITS 512       // 256u ref-grid noise + 8.5*sigma f16 err (R21/R23-verified)
#define SCALE 4194304.0f       // 2^22
#define BIAS 0.5f
#define NBLK 256               // k1 grid

typedef __attribute__((ext_vector_type(8))) _Float16 half8v;  // 8 f16 (4 VGPRs)
typedef __attribute__((ext_vector_type(16))) float f32x16;
typedef __attribute__((ext_vector_type(4))) float f32x4;
typedef __attribute__((ext_vector_type(4))) int i32x4;

// ws layout:
//   0       double lossSlots[256]  (per-block partials, no memset needed)
//   2048    float  c2_ref[512]
//   4096    float  c2fix[512]
//   6144    ushort cb_f16 chunks [g][code][8 f16], c*2048  (65536 B)
//   71680   float  cbT[64][512]  (131072 B) -> ends 202752
#define WS_SLOTS 0
#define WS_C2REF 2048
#define WS_C2FIX 4096
#define WS_CBH   6144
#define WS_CBT   71680

// LDS layout (71.9 KB):
#define L_CBH   0          // 65536 (cb_f16 for MFMA; reused as f32 half-codebook later)
#define L_C2F   65536      // 2048
#define L_QUEUE 67584      // int[512]
#define L_QCNT  69632      // int (+pad)
#define L_WLS   69696      // double[16]
#define L_IDXS  69824      // int[512]
#define LDS_SZ  71872

__device__ __forceinline__ unsigned short f2h_bits(float v) {
    _Float16 h = (_Float16)v;
    unsigned short u;
    __builtin_memcpy(&u, &h, 2);
    return u;
}

__global__ void k0_prep(const float* __restrict__ cb, char* __restrict__ ws) {
#pragma clang fp contract(off)
    int k = blockIdx.x * 64 + threadIdx.x;
    if (k >= KCODES) return;
    const float* cr = cb + (size_t)k * CDIM;
    float r[8];
    #pragma unroll
    for (int j = 0; j < 8; ++j) r[j] = cr[j] * cr[j];
    #pragma unroll
    for (int t = 1; t < 8; ++t)
        #pragma unroll
        for (int j = 0; j < 8; ++j) r[j] += cr[8 * t + j] * cr[8 * t + j];
    ((float*)(ws + WS_C2REF))[k] = ((r[0] + r[1]) + (r[2] + r[3])) + ((r[4] + r[5]) + (r[6] + r[7]));
    float acc = 0.f;
    #pragma unroll
    for (int i = 0; i < CDIM; ++i) acc = fmaf(cr[i], cr[i], acc);
    ((float*)(ws + WS_C2FIX))[k] = (acc + BIAS) * SCALE;
    unsigned short* hi = (unsigned short*)(ws + WS_CBH);
    #pragma unroll
    for (int g = 0; g < 8; ++g)
        #pragma unroll
        for (int j = 0; j < 8; ++j)
            hi[((size_t)(g * KCODES + k)) * 8 + j] = f2h_bits(cr[g * 8 + j] * 2048.0f);
    float* cbT = (float*)(ws + WS_CBT);
    #pragma unroll
    for (int i = 0; i < CDIM; ++i) cbT[i * KCODES + k] = cr[i];
}

// 1024 threads = 16 waves, 512 px/block, 256 blocks (R23 structure).
// Epilogue gathers from LDS (f32 codebook re-staged in 2 halves) instead of L2 scatter.
__global__ __launch_bounds__(1024)
void k1_mfma(const float* __restrict__ z_e,
             const float* __restrict__ cb,
             char* __restrict__ ws,
             float* __restrict__ out) {
#pragma clang fp contract(off)
    extern __shared__ char smem[];
    int*    queue = (int*)(smem + L_QUEUE);
    int*    qcnt  = (int*)(smem + L_QCNT);
    double* wls   = (double*)(smem + L_WLS);
    int*    idxs  = (int*)(smem + L_IDXS);
    float*  ldsf  = (float*)smem;        // f32 half-codebook [code][32ch] (epilogue)

    const int tid  = threadIdx.x;
    const int lane = tid & 63;
    const int wav  = tid >> 6;          // 0..15
    const int h    = lane >> 5;
    const int c    = lane & 31;

    const int pxblk = blockIdx.x * 512;
    const int b     = pxblk >> 12;
    const int hwb   = pxblk & 4095;
    const float* zb = z_e + (size_t)b * B_STRIDE;

    // ---- stage cb_f16 (64KB) + c2fix (2KB) to LDS
    if (tid == 0) *qcnt = 0;
    {
        const uint4* src = (const uint4*)(ws + WS_CBH);
        uint4* dst = (uint4*)smem;
        #pragma unroll
        for (int i = 0; i < 4; ++i)
            dst[i * 1024 + tid] = src[i * 1024 + tid];
        if (tid < 128)
            ((uint4*)(smem + L_C2F))[tid] = ((const uint4*)(ws + WS_C2FIX))[tid];
    }
    __syncthreads();

    const int lpx = wav * 32 + c;        // block-local pixel (0..511)
    const int hw  = hwb + lpx;

    // ---- z fragments: f16(-4096*z), single chain (R21/R23-verified)
    half8v zh[4];
    #pragma unroll
    for (int s = 0; s < 4; ++s) {
        float zf[8];
        #pragma unroll
        for (int j = 0; j < 8; ++j)
            zf[j] = zb[(size_t)(s * 16 + h * 8 + j) * CH_STRIDE + hw];
        half8v vh;
        #pragma unroll
        for (int j = 0; j < 8; ++j)
            vh[j] = (_Float16)(zf[j] * -4096.0f);
        zh[s] = vh;
    }

    // ---- MFMA scores + fixed-point min-track (cb_f16 from LDS)
    const float* c2f = (const float*)(smem + L_C2F);
    uint32_t m1 = 0xFFFFFFFFu, m2 = 0xFFFFFFFFu;

    for (int t = 0; t < 16; ++t) {
        int rbase = t * 32 + 4 * h;
        f32x16 acc;
        #pragma unroll
        for (int g = 0; g < 4; ++g) {
            f32x4 q = *(const f32x4*)(c2f + rbase + 8 * g);
            #pragma unroll
            for (int i = 0; i < 4; ++i) acc[4 * g + i] = q[i];
        }
        #pragma unroll
        for (int s = 0; s < 4; ++s) {
            int chunk = (2 * s + h) * KCODES + t * 32 + c;
            half8v a = *(const half8v*)(smem + L_CBH + (size_t)chunk * 16);
            acc = __builtin_amdgcn_mfma_f32_32x32x16_f16(a, zh[s], acc, 0, 0, 0);
        }
        #pragma unroll
        for (int i = 0; i < 16; ++i) {
            uint32_t code = (uint32_t)(t * 32 + 4 * h + (i & 3) + 8 * (i >> 2));
            uint32_t u = (((uint32_t)acc[i]) << 9) | code;
            uint32_t mx = m1 > u ? m1 : u;
            m2 = m2 < mx ? m2 : mx;
            m1 = m1 < u ? m1 : u;
        }
    }

    {   // merge lanes l and l^32 (same pixel)
        uint32_t o1 = (uint32_t)__shfl_xor((int)m1, 32);
        uint32_t o2 = (uint32_t)__shfl_xor((int)m2, 32);
        uint32_t mx  = m1 > o1 ? m1 : o1;
        uint32_t mn2 = m2 < o2 ? m2 : o2;
        m2 = mn2 < mx ? mn2 : mx;
        m1 = m1 < o1 ? m1 : o1;
    }

    // provisional idx + flag queue (owner lane h==0)
    if (h == 0) {
        idxs[lpx] = (int)(m1 & 0x1FFu);
        if ((int)((m2 >> 9) - (m1 >> 9)) < MARGIN_UNITS) {
            int pos = atomicAdd(qcnt, 1);
            queue[pos] = lpx;
        }
    }
    __syncthreads();

    // ---- batched exact resolve (R12/R16/R21-verified reference math), 16-wave
    {
        const float* c2r = (const float*)(ws + WS_C2REF);
        const float* cbT = (const float*)(ws + WS_CBT);
        const int nf = *qcnt;
        #pragma unroll 1
        for (int q = wav; q < nf; q += 16) {
            int pl = queue[q];
            int hwq = hwb + pl;
            float a[8] = {0.f,0.f,0.f,0.f,0.f,0.f,0.f,0.f};
            float r[8] = {0.f,0.f,0.f,0.f,0.f,0.f,0.f,0.f};
            #pragma unroll 1
            for (int ib = 0; ib < 8; ++ib) {
                float zr[8];
                #pragma unroll
                for (int i = 0; i < 8; ++i)
                    zr[i] = zb[(size_t)(ib * 8 + i) * CH_STRIDE + hwq];
                #pragma unroll
                for (int i = 0; i < 8; ++i) {
                    float zi = zr[i];
                    r[i] += zi * zi;                       // ref pairwise-8 order
                    const float* ct = cbT + (size_t)(ib * 8 + i) * KCODES + lane;
                    #pragma unroll
                    for (int k = 0; k < 8; ++k)
                        a[k] = fmaf(zi, ct[k * 64], a[k]); // ascending i per code
                }
            }
            float A = ((r[0] + r[1]) + (r[2] + r[3])) + ((r[4] + r[5]) + (r[6] + r[7]));
            float best = 3.4e38f; int bidx = 0x7FFFFFFF;
            #pragma unroll
            for (int k = 0; k < 8; ++k) {
                float d = (A - 2.0f * a[k]) + c2r[k * 64 + lane];
                if (d < best) { best = d; bidx = k * 64 + lane; }
            }
            for (int off = 32; off; off >>= 1) {
                float ob = __shfl_down(best, off);
                int   oi = __shfl_down(bidx, off);
                if (ob < best || (ob == best && oi < bidx)) { best = ob; bidx = oi; }
            }
            if (lane == 0) idxs[pl] = bidx;
        }
    }
    __syncthreads();

    // idx out (final) + grab own/gather indices before LDS codebook overwrite
    const int idxv = idxs[lpx];
    if (h == 0) out[IDXOUT_OFF + pxblk + lpx] = (float)idxv;
    const int px0 = (wav & 1) * 256 + lane * 4;   // 4 consecutive pixels (epilogue B)
    const int chb = wav >> 1;                     // channel sub-lane 0..7
    const i32x4 i4 = *(const i32x4*)&idxs[px0];

    // ---- epilogues in 2 channel-halves; f32 codebook staged to LDS per half.
    float lsum = 0.f;
    float* obase = out + (size_t)b * B_STRIDE + hwb;
    #pragma unroll 1
    for (int h2 = 0; h2 < 2; ++h2) {
        __syncthreads();   // previous users of ldsf region done
        // stage cb f32 channels [h2*32, h2*32+32) -> ldsf[code][32]
        #pragma unroll
        for (int i = 0; i < 16; ++i) {
            int linear = tid + i * 1024;          // < 16384
            int code = linear >> 3;
            int m = linear & 7;
            *(f32x4*)&ldsf[code * 32 + m * 4] =
                *(const f32x4*)(cb + (size_t)code * CDIM + h2 * 32 + m * 4);
        }
        __syncthreads();

        // loss part (s in {2*h2, 2*h2+1}): own-pixel rows from LDS
        #pragma unroll
        for (int si = 0; si < 2; ++si) {
            int s = 2 * h2 + si;
            int lch = si * 16 + h * 8;            // local channel 0..31
            f32x4 g0 = *(const f32x4*)&ldsf[idxv * 32 + lch];
            f32x4 g1 = *(const f32x4*)&ldsf[idxv * 32 + lch + 4];
            #pragma unroll
            for (int j = 0; j < 8; ++j) {
                float zq = (j < 4) ? g0[j] : g1[j - 4];
                float zv = (float)zh[s][j] * -2.44140625e-4f;
                float d = zq - zv;
                lsum = fmaf(d, d, lsum);
            }
        }

        // z_q streaming write for channels [h2*32, h2*32+32): gathers from LDS
        #pragma unroll
        for (int p = 0; p < 4; ++p) {
            int lch = p * 8 + chb;                // local channel 0..31
            int ch = h2 * 32 + lch;
            f32x4 v;
            v[0] = ldsf[i4[0] * 32 + lch];
            v[1] = ldsf[i4[1] * 32 + lch];
            v[2] = ldsf[i4[2] * 32 + lch];
            v[3] = ldsf[i4[3] * 32 + lch];
            *(f32x4*)(obase + (size_t)ch * CH_STRIDE + px0) = v;
        }
    }

    {   // per-wave loss reduce -> per-block slot (no atomics, no memset)
        double dl = (double)lsum;
        for (int off = 32; off; off >>= 1) dl += __shfl_down(dl, off);
        if (lane == 0) wls[wav] = dl;
        __syncthreads();
        if (tid == 0) {
            double s = 0.0;
            #pragma unroll
            for (int i = 0; i < 16; ++i) s += wls[i];
            ((double*)(ws + WS_SLOTS))[blockIdx.x] = s;
        }
    }
}

__global__ void k4_loss(float* __restrict__ out, const char* __restrict__ ws) {
    const double* slots = (const double*)(ws + WS_SLOTS);
    int lane = threadIdx.x;
    double s = 0.0;
    #pragma unroll
    for (int i = 0; i < NBLK / 64; ++i) s += slots[lane + i * 64];
    for (int off = 32; off; off >>= 1) s += __shfl_down(s, off);
    if (lane == 0) out[LOSS_OFF] = (float)(1.25 * s / (double)ZQ_SIZE);
}

extern "C" void kernel_launch(void* const* d_in, const int* in_sizes, int n_in,
                              void* d_out, int out_size, void* d_ws, size_t ws_size,
                              hipStream_t stream) {
    const float* z_e = (const float*)d_in[0];
    const float* cb  = (const float*)d_in[1];
    float* out = (float*)d_out;
    char* ws = (char*)d_ws;

    k0_prep<<<8, 64, 0, stream>>>(cb, ws);
    k1_mfma<<<NBLK, 1024, LDS_SZ, stream>>>(z_e, cb, ws, out);
    k4_loss<<<1, 64, 0, stream>>>(out, ws);
}

// Round 25
// 62.902 us; speedup vs baseline: 2.0955x; 1.2235x over previous
//
#include <hip/hip_runtime.h>
#include <hip/hip_bf16.h>
#include <stdint.h>

// z_e (32,64,64,64) f32, codebook (512,64) f32.
// d_out (f32): [0..8388607] z_q (B,C,H,W); [8388608] loss; [8388609..] indices as float.
#define NPIX 131072
#define CDIM 64
#define KCODES 512
#define ZQ_SIZE 8388608
#define LOSS_OFF 8388608
#define IDXOUT_OFF 8388609
#define CH_STRIDE 4096
#define B_STRIDE 262144
#define MARGIN_UNITS 512       // 256u ref-grid noise + 8.5*sigma f16 err (R21/R23-verified)
#define SCALE 4194304.0f       // 2^22
#define BIAS 0.5f
#define NBLK 256               // k1 grid

typedef __attribute__((ext_vector_type(8))) _Float16 half8v;  // 8 f16 (4 VGPRs)
typedef __attribute__((ext_vector_type(16))) float f32x16;
typedef __attribute__((ext_vector_type(4))) float f32x4;
typedef __attribute__((ext_vector_type(4))) int i32x4;

// ws layout:
//   0       double lossSlots[256]  (per-block partials)
//   2048    float  c2_ref[512]
//   4096    float  c2fix[512]
//   6144    ushort cb_f16 chunks [g][code][8 f16], c*2048  (65536 B)
//   71680   float  cbT[64][512]  (131072 B) — also the epilogue staging source
#define WS_SLOTS 0
#define WS_C2REF 2048
#define WS_C2FIX 4096
#define WS_CBH   6144
#define WS_CBT   71680

// LDS layout (71.9 KB):
#define L_CBH   0          // 65536 (cb_f16 for MFMA; reused as f32 [32ch][512] halves later)
#define L_C2F   65536      // 2048
#define L_QUEUE 67584      // int[512]  (dead after resolve)
#define L_QCNT  69632      // int (+pad)
#define L_WLS   69696      // double[16]
#define L_IDXS  69824      // int[512]
#define LDS_SZ  71872

__device__ __forceinline__ unsigned short f2h_bits(float v) {
    _Float16 h = (_Float16)v;
    unsigned short u;
    __builtin_memcpy(&u, &h, 2);
    return u;
}

__global__ void k0_prep(const float* __restrict__ cb, char* __restrict__ ws) {
#pragma clang fp contract(off)
    int k = blockIdx.x * 64 + threadIdx.x;
    if (k >= KCODES) return;
    const float* cr = cb + (size_t)k * CDIM;
    float r[8];
    #pragma unroll
    for (int j = 0; j < 8; ++j) r[j] = cr[j] * cr[j];
    #pragma unroll
    for (int t = 1; t < 8; ++t)
        #pragma unroll
        for (int j = 0; j < 8; ++j) r[j] += cr[8 * t + j] * cr[8 * t + j];
    ((float*)(ws + WS_C2REF))[k] = ((r[0] + r[1]) + (r[2] + r[3])) + ((r[4] + r[5]) + (r[6] + r[7]));
    float acc = 0.f;
    #pragma unroll
    for (int i = 0; i < CDIM; ++i) acc = fmaf(cr[i], cr[i], acc);
    ((float*)(ws + WS_C2FIX))[k] = (acc + BIAS) * SCALE;
    unsigned short* hi = (unsigned short*)(ws + WS_CBH);
    #pragma unroll
    for (int g = 0; g < 8; ++g)
        #pragma unroll
        for (int j = 0; j < 8; ++j)
            hi[((size_t)(g * KCODES + k)) * 8 + j] = f2h_bits(cr[g * 8 + j] * 2048.0f);
    float* cbT = (float*)(ws + WS_CBT);
    #pragma unroll
    for (int i = 0; i < CDIM; ++i) cbT[i * KCODES + k] = cr[i];
}

// 1024 threads = 16 waves, 512 px/block, 256 blocks.
// Epilogue gathers from LDS in [ch][code] layout: bank = code%32 -> spread.
__global__ __launch_bounds__(1024)
void k1_mfma(const float* __restrict__ z_e,
             const float* __restrict__ cb,
             char* __restrict__ ws,
             float* __restrict__ out) {
#pragma clang fp contract(off)
    extern __shared__ char smem[];
    int*    queue = (int*)(smem + L_QUEUE);
    int*    qcnt  = (int*)(smem + L_QCNT);
    double* wls   = (double*)(smem + L_WLS);
    int*    idxs  = (int*)(smem + L_IDXS);
    float*  ldsf  = (float*)smem;        // epilogue: f32 [32ch][512] half-codebook

    const int tid  = threadIdx.x;
    const int lane = tid & 63;
    const int wav  = tid >> 6;          // 0..15
    const int h    = lane >> 5;
    const int c    = lane & 31;

    const int pxblk = blockIdx.x * 512;
    const int b     = pxblk >> 12;
    const int hwb   = pxblk & 4095;
    const float* zb = z_e + (size_t)b * B_STRIDE;

    // ---- stage cb_f16 (64KB) + c2fix (2KB) to LDS
    if (tid == 0) *qcnt = 0;
    {
        const uint4* src = (const uint4*)(ws + WS_CBH);
        uint4* dst = (uint4*)smem;
        #pragma unroll
        for (int i = 0; i < 4; ++i)
            dst[i * 1024 + tid] = src[i * 1024 + tid];
        if (tid < 128)
            ((uint4*)(smem + L_C2F))[tid] = ((const uint4*)(ws + WS_C2FIX))[tid];
    }
    __syncthreads();

    const int lpx = wav * 32 + c;        // block-local pixel (0..511)
    const int hw  = hwb + lpx;

    // ---- z fragments: f16(-4096*z), single chain (R21/R23-verified)
    half8v zh[4];
    #pragma unroll
    for (int s = 0; s < 4; ++s) {
        float zf[8];
        #pragma unroll
        for (int j = 0; j < 8; ++j)
            zf[j] = zb[(size_t)(s * 16 + h * 8 + j) * CH_STRIDE + hw];
        half8v vh;
        #pragma unroll
        for (int j = 0; j < 8; ++j)
            vh[j] = (_Float16)(zf[j] * -4096.0f);
        zh[s] = vh;
    }

    // ---- MFMA scores + fixed-point min-track (cb_f16 from LDS)
    const float* c2f = (const float*)(smem + L_C2F);
    uint32_t m1 = 0xFFFFFFFFu, m2 = 0xFFFFFFFFu;

    for (int t = 0; t < 16; ++t) {
        int rbase = t * 32 + 4 * h;
        f32x16 acc;
        #pragma unroll
        for (int g = 0; g < 4; ++g) {
            f32x4 q = *(const f32x4*)(c2f + rbase + 8 * g);
            #pragma unroll
            for (int i = 0; i < 4; ++i) acc[4 * g + i] = q[i];
        }
        #pragma unroll
        for (int s = 0; s < 4; ++s) {
            int chunk = (2 * s + h) * KCODES + t * 32 + c;
            half8v a = *(const half8v*)(smem + L_CBH + (size_t)chunk * 16);
            acc = __builtin_amdgcn_mfma_f32_32x32x16_f16(a, zh[s], acc, 0, 0, 0);
        }
        #pragma unroll
        for (int i = 0; i < 16; ++i) {
            uint32_t code = (uint32_t)(t * 32 + 4 * h + (i & 3) + 8 * (i >> 2));
            uint32_t u = (((uint32_t)acc[i]) << 9) | code;
            uint32_t mx = m1 > u ? m1 : u;
            m2 = m2 < mx ? m2 : mx;
            m1 = m1 < u ? m1 : u;
        }
    }

    {   // merge lanes l and l^32 (same pixel)
        uint32_t o1 = (uint32_t)__shfl_xor((int)m1, 32);
        uint32_t o2 = (uint32_t)__shfl_xor((int)m2, 32);
        uint32_t mx  = m1 > o1 ? m1 : o1;
        uint32_t mn2 = m2 < o2 ? m2 : o2;
        m2 = mn2 < mx ? mn2 : mx;
        m1 = m1 < o1 ? m1 : o1;
    }

    // provisional idx + flag queue (owner lane h==0)
    if (h == 0) {
        idxs[lpx] = (int)(m1 & 0x1FFu);
        if ((int)((m2 >> 9) - (m1 >> 9)) < MARGIN_UNITS) {
            int pos = atomicAdd(qcnt, 1);
            queue[pos] = lpx;
        }
    }
    __syncthreads();

    // ---- batched exact resolve (R12/R16/R21-verified reference math), 16-wave
    {
        const float* c2r = (const float*)(ws + WS_C2REF);
        const float* cbT = (const float*)(ws + WS_CBT);
        const int nf = *qcnt;
        #pragma unroll 1
        for (int q = wav; q < nf; q += 16) {
            int pl = queue[q];
            int hwq = hwb + pl;
            float a[8] = {0.f,0.f,0.f,0.f,0.f,0.f,0.f,0.f};
            float r[8] = {0.f,0.f,0.f,0.f,0.f,0.f,0.f,0.f};
            #pragma unroll 1
            for (int ib = 0; ib < 8; ++ib) {
                float zr[8];
                #pragma unroll
                for (int i = 0; i < 8; ++i)
                    zr[i] = zb[(size_t)(ib * 8 + i) * CH_STRIDE + hwq];
                #pragma unroll
                for (int i = 0; i < 8; ++i) {
                    float zi = zr[i];
                    r[i] += zi * zi;                       // ref pairwise-8 order
                    const float* ct = cbT + (size_t)(ib * 8 + i) * KCODES + lane;
                    #pragma unroll
                    for (int k = 0; k < 8; ++k)
                        a[k] = fmaf(zi, ct[k * 64], a[k]); // ascending i per code
                }
            }
            float A = ((r[0] + r[1]) + (r[2] + r[3])) + ((r[4] + r[5]) + (r[6] + r[7]));
            float best = 3.4e38f; int bidx = 0x7FFFFFFF;
            #pragma unroll
            for (int k = 0; k < 8; ++k) {
                float d = (A - 2.0f * a[k]) + c2r[k * 64 + lane];
                if (d < best) { best = d; bidx = k * 64 + lane; }
            }
            for (int off = 32; off; off >>= 1) {
                float ob = __shfl_down(best, off);
                int   oi = __shfl_down(bidx, off);
                if (ob < best || (ob == best && oi < bidx)) { best = ob; bidx = oi; }
            }
            if (lane == 0) idxs[pl] = bidx;
        }
    }
    __syncthreads();

    // idx out (final) + grab indices before LDS codebook overwrite
    const int idxv = idxs[lpx];
    if (h == 0) out[IDXOUT_OFF + pxblk + lpx] = (float)idxv;
    const int px0 = (wav & 1) * 256 + lane * 4;   // 4 consecutive pixels (epilogue B)
    const int chb = wav >> 1;                     // channel sub-lane 0..7
    const i32x4 i4 = *(const i32x4*)&idxs[px0];

    // ---- epilogues in 2 channel-halves; cbT staged to LDS as [32ch][512] per half
    float lsum = 0.f;
    float* obase = out + (size_t)b * B_STRIDE + hwb;
    #pragma unroll 1
    for (int h2 = 0; h2 < 2; ++h2) {
        __syncthreads();   // previous users of ldsf region done
        {   // stage cbT channels [h2*32, h2*32+32) -> ldsf[lch][code] (64KB, coalesced)
            const f32x4* src = (const f32x4*)((const float*)(ws + WS_CBT) + h2 * 32 * KCODES);
            f32x4* dst = (f32x4*)ldsf;
            #pragma unroll
            for (int i = 0; i < 4; ++i)
                dst[tid + i * 1024] = src[tid + i * 1024];
        }
        __syncthreads();

        // loss part (s in {2*h2, 2*h2+1}): own-code reads, bank = idxv%32 (spread)
        #pragma unroll
        for (int si = 0; si < 2; ++si) {
            int s = 2 * h2 + si;
            int lch0 = si * 16 + h * 8;           // local channel 0..31
            #pragma unroll
            for (int j = 0; j < 8; ++j) {
                float zq = ldsf[(lch0 + j) * KCODES + idxv];
                float zv = (float)zh[s][j] * -2.44140625e-4f;
                float d = zq - zv;
                lsum = fmaf(d, d, lsum);
            }
        }

        // z_q streaming write for channels [h2*32, h2*32+32): bank = code%32 (spread)
        #pragma unroll
        for (int p = 0; p < 4; ++p) {
            int lch = p * 8 + chb;                // local channel 0..31
            int ch = h2 * 32 + lch;
            const float* row = ldsf + lch * KCODES;
            f32x4 v;
            v[0] = row[i4[0]];
            v[1] = row[i4[1]];
            v[2] = row[i4[2]];
            v[3] = row[i4[3]];
            *(f32x4*)(obase + (size_t)ch * CH_STRIDE + px0) = v;
        }
    }

    {   // per-wave loss reduce -> per-block slot (no atomics)
        double dl = (double)lsum;
        for (int off = 32; off; off >>= 1) dl += __shfl_down(dl, off);
        if (lane == 0) wls[wav] = dl;
        __syncthreads();
        if (tid == 0) {
            double s = 0.0;
            #pragma unroll
            for (int i = 0; i < 16; ++i) s += wls[i];
            ((double*)(ws + WS_SLOTS))[blockIdx.x] = s;
        }
    }
}

__global__ void k4_loss(float* __restrict__ out, const char* __restrict__ ws) {
    const double* slots = (const double*)(ws + WS_SLOTS);
    int lane = threadIdx.x;
    double s = 0.0;
    #pragma unroll
    for (int i = 0; i < NBLK / 64; ++i) s += slots[lane + i * 64];
    for (int off = 32; off; off >>= 1) s += __shfl_down(s, off);
    if (lane == 0) out[LOSS_OFF] = (float)(1.25 * s / (double)ZQ_SIZE);
}

extern "C" void kernel_launch(void* const* d_in, const int* in_sizes, int n_in,
                              void* d_out, int out_size, void* d_ws, size_t ws_size,
                              hipStream_t stream) {
    const float* z_e = (const float*)d_in[0];
    const float* cb  = (const float*)d_in[1];
    float* out = (float*)d_out;
    char* ws = (char*)d_ws;

    k0_prep<<<8, 64, 0, stream>>>(cb, ws);
    k1_mfma<<<NBLK, 1024, LDS_SZ, stream>>>(z_e, cb, ws, out);
    k4_loss<<<1, 64, 0, stream>>>(out, ws);
}